// Round 1
// baseline (377.526 us; speedup 1.0000x reference)
//
#include <hip/hip_runtime.h>
#include <math.h>

#define N_NODES 8192
#define N_EDGES 262144
#define INV_SQRT3 0.5773502691896258f

typedef __attribute__((ext_vector_type(8))) _Float16 half8;
typedef __attribute__((ext_vector_type(4))) float floatx4;

#define MF16(a,b,c) __builtin_amdgcn_mfma_f32_16x16x32_f16(a,b,c,0,0,0)

__device__ __forceinline__ float sspf(float x){
    // softplus(x) - ln2 via hw v_exp/v_log
    return (x > 20.0f) ? (x - 0.69314718f)
                       : (__logf(1.0f + __expf(x)) - 0.69314718f);
}

// ---------------------------------------------------------------------------
// Node kernel (factored sc einsum): sc = einsum('nu,nuv->nv', s, T),
// T[n,u,v] = einsum('na,uav->nuv', attrs, Ws). 4 nodes/block.
// Also computes q, qd (= Wd^T q, scales folded), stored PERMUTED:
// qdbuf[n][col*8+slot], slot = {qd0[c], qd0[c+16], qd1[3c..+2], qd1[3(c+16)..+2]}.
// NOW also emits feats16 (fp16 copy of feats) in the same load loop,
// replacing the separate convert_kernel launch.
// ---------------------------------------------------------------------------
__global__ __launch_bounds__(256) void node_kernel(
    const float* __restrict__ feats, const float* __restrict__ attrs,
    const float* __restrict__ Wq0, const float* __restrict__ Wq1,
    const float* __restrict__ Wd0, const float* __restrict__ Wd1,
    const float* __restrict__ Ws0, const float* __restrict__ Ws1,
    float* __restrict__ qdbuf, float* __restrict__ out,
    _Float16* __restrict__ feats16)
{
    __shared__ float sa[4][16];
    __shared__ float sT[4][4][32];
    __shared__ float Tl[2][4][1152];   // T, rows stride 36
    __shared__ float qT[4][4][32];
    __shared__ float qsh[4][128];

    const int t  = threadIdx.x;
    const int nb = blockIdx.x * 4;

    const float inv_sqrt32 = 0.17677669529663687f;
    const float sc_scale   = 0.04419417382415922f;
    const float d_scale    = 0.022097086912079608f;

    for (int i = t; i < 512; i += 256){
        int nn = i >> 7, r = i & 127;
        int p = r >> 5, u = r & 31;
        int off = (p==0) ? u : 32 + u*3 + (p-1);
        float val = feats[(size_t)(nb+nn)*128 + off];
        sT[nn][p][u] = val;
        feats16[(size_t)(nb+nn)*128 + off] = (_Float16)val;
    }
    if (t < 64) sa[t>>4][t&15] = attrs[(size_t)(nb + (t>>4))*16 + (t&15)];
    __syncthreads();

    const int v  = t & 31;
    const int g5 = (t >> 5) & 3;
    const int hi = t >> 7;

    {
        const float* __restrict__ Wm = hi ? Ws1 : Ws0;
        float sar[4][16];
        #pragma unroll
        for (int nn = 0; nn < 4; ++nn)
            #pragma unroll
            for (int a = 0; a < 16; ++a) sar[nn][a] = sa[nn][a];
        #pragma unroll
        for (int uu = 0; uu < 8; ++uu){
            int u = g5*8 + uu;
            float a0=0.f, a1=0.f, a2=0.f, a3=0.f;
            #pragma unroll
            for (int a = 0; a < 16; ++a){
                float w = Wm[(u*16 + a)*32 + v];
                a0 += sar[0][a]*w; a1 += sar[1][a]*w;
                a2 += sar[2][a]*w; a3 += sar[3][a]*w;
            }
            Tl[hi][0][v*36+u] = a0; Tl[hi][1][v*36+u] = a1;
            Tl[hi][2][v*36+u] = a2; Tl[hi][3][v*36+u] = a3;
        }
    }
    __syncthreads();

    const int p  = g5;
    const int n0 = hi*2, n1 = n0 + 1;
    const int mm = (p==0) ? 0 : 1;
    const float* __restrict__ Wqp = (p==0) ? Wq0 : Wq1;
    const float* __restrict__ Wdp = (p==0) ? Wd0 : Wd1;
    const int oidx = (p==0) ? v : 32 + v*3 + (p-1);

    float c0=0.f, c1=0.f;
    #pragma unroll
    for (int uc = 0; uc < 8; ++uc){
        float4 t0 = *(const float4*)&Tl[mm][n0][v*36 + uc*4];
        float4 t1 = *(const float4*)&Tl[mm][n1][v*36 + uc*4];
        float4 s0 = *(const float4*)&sT[n0][p][uc*4];
        float4 s1 = *(const float4*)&sT[n1][p][uc*4];
        c0 += t0.x*s0.x + t0.y*s0.y + t0.z*s0.z + t0.w*s0.w;
        c1 += t1.x*s1.x + t1.y*s1.y + t1.z*s1.z + t1.w*s1.w;
    }
    out[(size_t)(nb+n0)*128 + oidx] = c0 * sc_scale;
    out[(size_t)(nb+n1)*128 + oidx] = c1 * sc_scale;

    float q0=0.f, q1=0.f;
    #pragma unroll
    for (int u = 0; u < 32; ++u){
        float w = Wqp[u*32 + v];
        q0 += sT[n0][p][u] * w;
        q1 += sT[n1][p][u] * w;
    }
    qT[n0][p][v] = q0 * inv_sqrt32;
    qT[n1][p][v] = q1 * inv_sqrt32;
    __syncthreads();

    float d0=0.f, d1=0.f;
    #pragma unroll
    for (int u = 0; u < 32; ++u){
        float w = Wdp[u*32 + v];
        d0 += qT[n0][p][u] * w;
        d1 += qT[n1][p][u] * w;
    }
    float dsc = (p==0) ? d_scale : d_scale * INV_SQRT3;
    qsh[n0][oidx] = d0 * dsc;
    qsh[n1][oidx] = d1 * dsc;
    __syncthreads();

    for (int i = t; i < 512; i += 256){
        int nn = i >> 7, tt = i & 127;
        int col = tt >> 3, slot = tt & 7;
        int src;
        if      (slot == 0) src = col;
        else if (slot == 1) src = col + 16;
        else if (slot <  5) src = 32 + 3*col + (slot-2);
        else                src = 32 + 3*(col+16) + (slot-5);
        qdbuf[(size_t)(nb+nn)*128 + tt] = qsh[nn][src];
    }
}

// ---------------------------------------------------------------------------
// CSR build: histogram by dst -> exclusive scan -> scatter+REORDER.
// scatter writes the per-edge streams in CSR position order so the edge
// pass reads them SEQUENTIALLY.
// ---------------------------------------------------------------------------
__global__ __launch_bounds__(256) void count_kernel(
    const int* __restrict__ eidx, int* __restrict__ degb)
{
    int e = blockIdx.x*256 + threadIdx.x;
    atomicAdd(&degb[eidx[N_EDGES + e]], 1);
}

__global__ __launch_bounds__(256) void scan_kernel(
    const int* __restrict__ degb, int* __restrict__ rowstart,
    int* __restrict__ cursor)
{
    __shared__ int part[256];
    int t = threadIdx.x;
    int loc[32];
    int s = 0;
    #pragma unroll
    for (int i = 0; i < 32; ++i){ loc[i] = s; s += degb[t*32 + i]; }
    part[t] = s;
    __syncthreads();
    for (int d = 1; d < 256; d <<= 1){
        int v = (t >= d) ? part[t-d] : 0;
        __syncthreads();
        part[t] += v;
        __syncthreads();
    }
    int excl = part[t] - s;
    #pragma unroll
    for (int i = 0; i < 32; ++i){
        int v = excl + loc[i];
        rowstart[t*32 + i] = v;
        cursor[t*32 + i]   = v;
    }
    if (t == 255) rowstart[N_NODES] = excl + s;
}

__global__ __launch_bounds__(256) void scatter_kernel(
    const int* __restrict__ eidx, const float* __restrict__ emb,
    const float* __restrict__ eattr, int* __restrict__ cursor,
    int* __restrict__ srcp, _Float16* __restrict__ emb16p,
    float* __restrict__ eattrp)
{
    int e = blockIdx.x*256 + threadIdx.x;
    int p = atomicAdd(&cursor[eidx[N_EDGES + e]], 1);
    srcp[p] = eidx[e];
    *(float4*)(eattrp + (size_t)p*4) = *(const float4*)(eattr + (size_t)e*4);
    const float4* ep = (const float4*)(emb + (size_t)e*16);
    float4 v0 = ep[0], v1 = ep[1], v2 = ep[2], v3 = ep[3];
    half8 h0, h1;
    h0[0]=(_Float16)v0.x; h0[1]=(_Float16)v0.y; h0[2]=(_Float16)v0.z; h0[3]=(_Float16)v0.w;
    h0[4]=(_Float16)v1.x; h0[5]=(_Float16)v1.y; h0[6]=(_Float16)v1.z; h0[7]=(_Float16)v1.w;
    h1[0]=(_Float16)v2.x; h1[1]=(_Float16)v2.y; h1[2]=(_Float16)v2.z; h1[3]=(_Float16)v2.w;
    h1[4]=(_Float16)v3.x; h1[5]=(_Float16)v3.y; h1[6]=(_Float16)v3.z; h1[7]=(_Float16)v3.w;
    *(half8*)(emb16p + (size_t)p*16)     = h0;
    *(half8*)(emb16p + (size_t)p*16 + 8) = h1;
}

// ---------------------------------------------------------------------------
// FUSED edge pass (k-chain + v-chain in one loop).
// Key identity: msg = sqrt(relu(alpha))*v = (sqrt(ev)/sqrt(z))*v, and
// rsqrt(z) factors out of the per-node edge sum. So per edge we compute
// d -> ev -> coef=sqrt(ev) (k-weights) AND the v-chain, accumulating
// zacc += ev and macc += coef*v in the SAME iteration; scale by rsqrt(zacc)
// once at the end. This reads every per-edge stream + the 256 B/edge
// feats16 gather ONCE (was twice), kills cfbuf/zbuf, and doubles the
// independent compute per loaded byte (64 MFMA/tile) to hide load latency.
// GEMM1 for k and v share the A-fragment: h_k staged at stag cols 0..63,
// h_v at 64..127, one LDS round-trip for both. Same-wave DS ops are
// in-order, so the w_k reads before the w_v overlay writes are safe
// (same property the previous kernel relied on).
// LDS: 2x weight sets (57344 B) + stag (17408 B) = 74752 B -> 2 blocks/CU.
// mfma_f32_16x16x32_f16 layouts (measured, learn_hip m89/m120):
// A[m=lane&15][k=quad*8+j]; B[k=quad*8+j][n=lane&15]; C col=lane&15,
// row=quad*4+reg.
// ---------------------------------------------------------------------------
__global__ __launch_bounds__(256, 2) void edge_fused(
    const _Float16* __restrict__ feats16, const _Float16* __restrict__ emb16p,
    const float* __restrict__ eattrp, const int* __restrict__ srcp,
    const float* __restrict__ Wk1,  const float* __restrict__ Wk2,
    const float* __restrict__ Wlk0, const float* __restrict__ Wlk1,
    const float* __restrict__ Wv1,  const float* __restrict__ Wv2,
    const float* __restrict__ Wlv0, const float* __restrict__ Wlv1,
    const float* __restrict__ qdbuf,
    const int* __restrict__ rowstart,
    float* __restrict__ out)
{
    __shared__ half8 fW1[2][4][64];
    __shared__ half8 fW2[2][16][64];
    __shared__ half8 fL0[2][4][64];
    __shared__ half8 fL1[2][4][64];
    __shared__ _Float16 stag[4][16][136];

    const int t    = threadIdx.x;
    const int lane = t & 63;
    const int col  = lane & 15;
    const int quad = lane >> 4;
    const int g    = t >> 6;

    // ---- preload BOTH weight sets (scales folded) ----
    #pragma unroll
    for (int kv = 0; kv < 2; ++kv){
        const float* __restrict__ W1 = kv ? Wv1  : Wk1;
        const float* __restrict__ W2 = kv ? Wv2  : Wk2;
        const float* __restrict__ L0 = kv ? Wlv0 : Wlk0;
        const float* __restrict__ L1 = kv ? Wlv1 : Wlk1;
        {
            half8 f;
            #pragma unroll
            for (int j = 0; j < 8; ++j){
                int k = quad*8 + j;
                f[j] = (k < 16) ? (_Float16)(W1[k*64 + g*16 + col] * 0.25f) : (_Float16)0.f;
            }
            fW1[kv][g][lane] = f;
        }
        #pragma unroll
        for (int ff = 0; ff < 4; ++ff){
            int fr = g*4 + ff, tile = fr >> 1, s = fr & 1;
            half8 f;
            #pragma unroll
            for (int j = 0; j < 8; ++j)
                f[j] = (_Float16)(W2[(s*32 + quad*8 + j)*128 + tile*16 + col] * 0.125f);
            fW2[kv][fr][lane] = f;
        }
        {
            int tile = g >> 1, s = g & 1;
            half8 f0, f1;
            #pragma unroll
            for (int j = 0; j < 8; ++j){
                int k = (s*32 + quad*8 + j)*32 + tile*16 + col;
                f0[j] = (_Float16)(L0[k] * 0.125f);
                f1[j] = (_Float16)(L1[k] * 0.125f);
            }
            fL0[kv][g][lane] = f0; fL1[kv][g][lane] = f1;
        }
    }
    __syncthreads();     // the only block-wide barrier

    const floatx4 zzero = {0.f, 0.f, 0.f, 0.f};

    const int n  = blockIdx.x*4 + g;
    const int r0 = rowstart[n];
    const int dcount = rowstart[n+1] - r0;

    const float* qdp = qdbuf + (size_t)n*128 + col*8;
    float4 qa = *(const float4*)qdp;
    float4 qb = *(const float4*)(qdp + 4);

    float macc0=0.f, macc1=0.f, macc2=0.f, macc3=0.f;
    float macc4=0.f, macc5=0.f, macc6=0.f, macc7=0.f;
    float zacc = 0.f;

    for (int tb = 0; tb < dcount; tb += 16){
        int slot = tb + col;
        int pc = r0 + ((slot < dcount) ? slot : (dcount-1));

        // ---- A-fragment: emb16p rows SEQUENTIAL (K=16 padded to 32) ----
        half8 ea;
        if (quad < 2){
            ea = *(const half8*)(emb16p + (size_t)pc*16 + quad*8);
        } else {
            #pragma unroll
            for (int j = 0; j < 8; ++j) ea[j] = (_Float16)0.f;
        }

        const int srcm = srcp[pc];
        const _Float16* fsrc = feats16 + (size_t)srcm*128;
        float4 yv = *(const float4*)(eattrp + (size_t)pc*4);
        const float y0 = yv.x, y1a = yv.y, y1b = yv.z, y1c = yv.w;

        half8 hx = *(const half8*)(fsrc + quad*8);
        float xs0[8];
        #pragma unroll
        for (int j = 0; j < 8; ++j) xs0[j] = (float)hx[j];
        half8 hz0 = *(const half8*)(fsrc + 32 + quad*24);
        half8 hz1 = *(const half8*)(fsrc + 32 + quad*24 + 8);
        half8 hz2 = *(const half8*)(fsrc + 32 + quad*24 + 16);
        float x1s[24];
        #pragma unroll
        for (int j = 0; j < 8; ++j){
            x1s[j]      = (float)hz0[j];
            x1s[8 + j]  = (float)hz1[j];
            x1s[16 + j] = (float)hz2[j];
        }

        // ---- GEMM1 (k AND v, shared A) -> ssp -> h staging side-by-side ----
        floatx4 hA = MF16(ea, fW1[0][0][lane], zzero);
        floatx4 hB = MF16(ea, fW1[0][1][lane], zzero);
        floatx4 hC = MF16(ea, fW1[0][2][lane], zzero);
        floatx4 hD = MF16(ea, fW1[0][3][lane], zzero);
        floatx4 hE = MF16(ea, fW1[1][0][lane], zzero);
        floatx4 hF = MF16(ea, fW1[1][1][lane], zzero);
        floatx4 hG = MF16(ea, fW1[1][2][lane], zzero);
        floatx4 hH = MF16(ea, fW1[1][3][lane], zzero);
        #pragma unroll
        for (int r = 0; r < 4; ++r){
            stag[g][quad*4+r][      col] = (_Float16)sspf(hA[r]);
            stag[g][quad*4+r][ 16 + col] = (_Float16)sspf(hB[r]);
            stag[g][quad*4+r][ 32 + col] = (_Float16)sspf(hC[r]);
            stag[g][quad*4+r][ 48 + col] = (_Float16)sspf(hD[r]);
            stag[g][quad*4+r][ 64 + col] = (_Float16)sspf(hE[r]);
            stag[g][quad*4+r][ 80 + col] = (_Float16)sspf(hF[r]);
            stag[g][quad*4+r][ 96 + col] = (_Float16)sspf(hG[r]);
            stag[g][quad*4+r][112 + col] = (_Float16)sspf(hH[r]);
        }
        half8 a0k = *(const half8*)&stag[g][col][     quad*8];
        half8 a1k = *(const half8*)&stag[g][col][32 + quad*8];
        half8 a0v = *(const half8*)&stag[g][col][64 + quad*8];
        half8 a1v = *(const half8*)&stag[g][col][96 + quad*8];

        // ---- GEMM2 k: w_k = h_k @ Wk2 (overlay stag; same-wave DS in-order)
        floatx4 wc0 = MF16(a0k, fW2[0][ 0][lane], zzero); wc0 = MF16(a1k, fW2[0][ 1][lane], wc0);
        floatx4 wc1 = MF16(a0k, fW2[0][ 2][lane], zzero); wc1 = MF16(a1k, fW2[0][ 3][lane], wc1);
        floatx4 wc2 = MF16(a0k, fW2[0][ 4][lane], zzero); wc2 = MF16(a1k, fW2[0][ 5][lane], wc2);
        floatx4 wc3 = MF16(a0k, fW2[0][ 6][lane], zzero); wc3 = MF16(a1k, fW2[0][ 7][lane], wc3);
        floatx4 wc4 = MF16(a0k, fW2[0][ 8][lane], zzero); wc4 = MF16(a1k, fW2[0][ 9][lane], wc4);
        floatx4 wc5 = MF16(a0k, fW2[0][10][lane], zzero); wc5 = MF16(a1k, fW2[0][11][lane], wc5);
        floatx4 wc6 = MF16(a0k, fW2[0][12][lane], zzero); wc6 = MF16(a1k, fW2[0][13][lane], wc6);
        floatx4 wc7 = MF16(a0k, fW2[0][14][lane], zzero); wc7 = MF16(a1k, fW2[0][15][lane], wc7);
        #pragma unroll
        for (int r = 0; r < 4; ++r){
            stag[g][quad*4+r][  0+col] = (_Float16)wc0[r];
            stag[g][quad*4+r][ 16+col] = (_Float16)wc1[r];
            stag[g][quad*4+r][ 32+col] = (_Float16)wc2[r];
            stag[g][quad*4+r][ 48+col] = (_Float16)wc3[r];
            stag[g][quad*4+r][ 64+col] = (_Float16)wc4[r];
            stag[g][quad*4+r][ 80+col] = (_Float16)wc5[r];
            stag[g][quad*4+r][ 96+col] = (_Float16)wc6[r];
            stag[g][quad*4+r][112+col] = (_Float16)wc7[r];
        }
        half8 w0hk = *(const half8*)&stag[g][col][     quad*8];
        half8 w1hk = *(const half8*)&stag[g][col][32 + quad*8];
        half8 w2hk = *(const half8*)&stag[g][col][64 + quad*8];
        half8 w3hk = *(const half8*)&stag[g][col][96 + quad*8];

        // ---- GEMM2 v (reads above precede these overlay writes in-order) --
        wc0 = MF16(a0v, fW2[1][ 0][lane], zzero); wc0 = MF16(a1v, fW2[1][ 1][lane], wc0);
        wc1 = MF16(a0v, fW2[1][ 2][lane], zzero); wc1 = MF16(a1v, fW2[1][ 3][lane], wc1);
        wc2 = MF16(a0v, fW2[1][ 4][lane], zzero); wc2 = MF16(a1v, fW2[1][ 5][lane], wc2);
        wc3 = MF16(a0v, fW2[1][ 6][lane], zzero); wc3 = MF16(a1v, fW2[1][ 7][lane], wc3);
        wc4 = MF16(a0v, fW2[1][ 8][lane], zzero); wc4 = MF16(a1v, fW2[1][ 9][lane], wc4);
        wc5 = MF16(a0v, fW2[1][10][lane], zzero); wc5 = MF16(a1v, fW2[1][11][lane], wc5);
        wc6 = MF16(a0v, fW2[1][12][lane], zzero); wc6 = MF16(a1v, fW2[1][13][lane], wc6);
        wc7 = MF16(a0v, fW2[1][14][lane], zzero); wc7 = MF16(a1v, fW2[1][15][lane], wc7);
        #pragma unroll
        for (int r = 0; r < 4; ++r){
            stag[g][quad*4+r][  0+col] = (_Float16)wc0[r];
            stag[g][quad*4+r][ 16+col] = (_Float16)wc1[r];
            stag[g][quad*4+r][ 32+col] = (_Float16)wc2[r];
            stag[g][quad*4+r][ 48+col] = (_Float16)wc3[r];
            stag[g][quad*4+r][ 64+col] = (_Float16)wc4[r];
            stag[g][quad*4+r][ 80+col] = (_Float16)wc5[r];
            stag[g][quad*4+r][ 96+col] = (_Float16)wc6[r];
            stag[g][quad*4+r][112+col] = (_Float16)wc7[r];
        }

        // ---- uvu k: km directly in lin A-frag layout ----
        half8 fk0s0, fk0s1, fc0s0, fc0s1, fc1s0, fc1s1, fc2s0, fc2s1;
        #pragma unroll
        for (int j = 0; j < 8; ++j){
            float ww0=(float)w0hk[j], ww1=(float)w1hk[j];
            float ww2=(float)w2hk[j], ww3=(float)w3hk[j];
            float x0 = xs0[j];
            float xa = x1s[3*j], xb = x1s[3*j+1], xc = x1s[3*j+2];
            fk0s0[j] = (_Float16)(ww0 * x0 * y0);
            fk0s1[j] = (_Float16)(ww3 * (xa*y1a + xb*y1b + xc*y1c) * INV_SQRT3);
            fc0s0[j] = (_Float16)(ww1 * x0 * y1a);
            fc1s0[j] = (_Float16)(ww1 * x0 * y1b);
            fc2s0[j] = (_Float16)(ww1 * x0 * y1c);
            fc0s1[j] = (_Float16)(ww2 * xa * y0);
            fc1s1[j] = (_Float16)(ww2 * xb * y0);
            fc2s1[j] = (_Float16)(ww2 * xc * y0);
        }

        // ---- lin k + d dot + softmax pieces ----
        floatx4 k0a  = MF16(fk0s0, fL0[0][0][lane], zzero); k0a  = MF16(fk0s1, fL0[0][1][lane], k0a);
        floatx4 k0b  = MF16(fk0s0, fL0[0][2][lane], zzero); k0b  = MF16(fk0s1, fL0[0][3][lane], k0b);
        floatx4 kc0a = MF16(fc0s0, fL1[0][0][lane], zzero); kc0a = MF16(fc0s1, fL1[0][1][lane], kc0a);
        floatx4 kc0b = MF16(fc0s0, fL1[0][2][lane], zzero); kc0b = MF16(fc0s1, fL1[0][3][lane], kc0b);
        floatx4 kc1a = MF16(fc1s0, fL1[0][0][lane], zzero); kc1a = MF16(fc1s1, fL1[0][1][lane], kc1a);
        floatx4 kc1b = MF16(fc1s0, fL1[0][2][lane], zzero); kc1b = MF16(fc1s1, fL1[0][3][lane], kc1b);
        floatx4 kc2a = MF16(fc2s0, fL1[0][0][lane], zzero); kc2a = MF16(fc2s1, fL1[0][1][lane], kc2a);
        floatx4 kc2b = MF16(fc2s0, fL1[0][2][lane], zzero); kc2b = MF16(fc2s1, fL1[0][3][lane], kc2b);

        float cf0, cf1, cf2, cf3;
        #pragma unroll
        for (int r = 0; r < 4; ++r){
            float dd = k0a[r]*qa.x + k0b[r]*qa.y + kc0a[r]*qa.z + kc1a[r]*qa.w
                     + kc2a[r]*qb.x + kc0b[r]*qb.y + kc1b[r]*qb.z + kc2b[r]*qb.w;
            dd += __shfl_xor(dd, 1);
            dd += __shfl_xor(dd, 2);
            dd += __shfl_xor(dd, 4);
            dd += __shfl_xor(dd, 8);
            // cutoff const: diff = pos[src]-pos[src] == 0 (reference bug)
            bool valid = (tb + quad*4 + r) < dcount;
            float ev = valid ? (0.9048374180359595f * __expf(dd)) : 0.f;
            zacc += ev;
            float cf = sqrtf(ev);
            if (r==0) cf0 = cf; else if (r==1) cf1 = cf;
            else if (r==2) cf2 = cf; else cf3 = cf;
        }

        // ---- read back w_v, uvu v ----
        half8 w0hv = *(const half8*)&stag[g][col][     quad*8];
        half8 w1hv = *(const half8*)&stag[g][col][32 + quad*8];
        half8 w2hv = *(const half8*)&stag[g][col][64 + quad*8];
        half8 w3hv = *(const half8*)&stag[g][col][96 + quad*8];
        #pragma unroll
        for (int j = 0; j < 8; ++j){
            float ww0=(float)w0hv[j], ww1=(float)w1hv[j];
            float ww2=(float)w2hv[j], ww3=(float)w3hv[j];
            float x0 = xs0[j];
            float xa = x1s[3*j], xb = x1s[3*j+1], xc = x1s[3*j+2];
            fk0s0[j] = (_Float16)(ww0 * x0 * y0);
            fk0s1[j] = (_Float16)(ww3 * (xa*y1a + xb*y1b + xc*y1c) * INV_SQRT3);
            fc0s0[j] = (_Float16)(ww1 * x0 * y1a);
            fc1s0[j] = (_Float16)(ww1 * x0 * y1b);
            fc2s0[j] = (_Float16)(ww1 * x0 * y1c);
            fc0s1[j] = (_Float16)(ww2 * xa * y0);
            fc1s1[j] = (_Float16)(ww2 * xb * y0);
            fc2s1[j] = (_Float16)(ww2 * xc * y0);
        }

        // ---- lin v + weighted accumulate (coef = sqrt(ev), rz deferred) ---
        floatx4 v0a  = MF16(fk0s0, fL0[1][0][lane], zzero); v0a  = MF16(fk0s1, fL0[1][1][lane], v0a);
        floatx4 v0b  = MF16(fk0s0, fL0[1][2][lane], zzero); v0b  = MF16(fk0s1, fL0[1][3][lane], v0b);
        floatx4 vc0a = MF16(fc0s0, fL1[1][0][lane], zzero); vc0a = MF16(fc0s1, fL1[1][1][lane], vc0a);
        floatx4 vc0b = MF16(fc0s0, fL1[1][2][lane], zzero); vc0b = MF16(fc0s1, fL1[1][3][lane], vc0b);
        floatx4 vc1a = MF16(fc1s0, fL1[1][0][lane], zzero); vc1a = MF16(fc1s1, fL1[1][1][lane], vc1a);
        floatx4 vc1b = MF16(fc1s0, fL1[1][2][lane], zzero); vc1b = MF16(fc1s1, fL1[1][3][lane], vc1b);
        floatx4 vc2a = MF16(fc2s0, fL1[1][0][lane], zzero); vc2a = MF16(fc2s1, fL1[1][1][lane], vc2a);
        floatx4 vc2b = MF16(fc2s0, fL1[1][2][lane], zzero); vc2b = MF16(fc2s1, fL1[1][3][lane], vc2b);

        macc0 += cf0*v0a[0]  + cf1*v0a[1]  + cf2*v0a[2]  + cf3*v0a[3];
        macc1 += cf0*v0b[0]  + cf1*v0b[1]  + cf2*v0b[2]  + cf3*v0b[3];
        macc2 += cf0*vc0a[0] + cf1*vc0a[1] + cf2*vc0a[2] + cf3*vc0a[3];
        macc3 += cf0*vc1a[0] + cf1*vc1a[1] + cf2*vc1a[2] + cf3*vc1a[3];
        macc4 += cf0*vc2a[0] + cf1*vc2a[1] + cf2*vc2a[2] + cf3*vc2a[3];
        macc5 += cf0*vc0b[0] + cf1*vc0b[1] + cf2*vc0b[2] + cf3*vc0b[3];
        macc6 += cf0*vc1b[0] + cf1*vc1b[1] + cf2*vc1b[2] + cf3*vc1b[3];
        macc7 += cf0*vc2b[0] + cf1*vc2b[1] + cf2*vc2b[2] + cf3*vc2b[3];
    }

    // ---- reduce over quads; rsqrt(z) factored scaling; write out ----
    macc0 += __shfl_xor(macc0, 16); macc0 += __shfl_xor(macc0, 32);
    macc1 += __shfl_xor(macc1, 16); macc1 += __shfl_xor(macc1, 32);
    macc2 += __shfl_xor(macc2, 16); macc2 += __shfl_xor(macc2, 32);
    macc3 += __shfl_xor(macc3, 16); macc3 += __shfl_xor(macc3, 32);
    macc4 += __shfl_xor(macc4, 16); macc4 += __shfl_xor(macc4, 32);
    macc5 += __shfl_xor(macc5, 16); macc5 += __shfl_xor(macc5, 32);
    macc6 += __shfl_xor(macc6, 16); macc6 += __shfl_xor(macc6, 32);
    macc7 += __shfl_xor(macc7, 16); macc7 += __shfl_xor(macc7, 32);
    zacc  += __shfl_xor(zacc, 16);  zacc  += __shfl_xor(zacc, 32);
    // zacc is replicated across the 16 cols (each quad's value was already
    // col-replicated), so quad-only reduction yields the full z in all lanes.
    float rz = (zacc > 0.f) ? rsqrtf(zacc) : 0.f;

    if (lane < 16){
        float* op = out + (size_t)n*128;
        op[col]                 += macc0 * rz;
        op[col + 16]            += macc1 * rz;
        op[32 + 3*col + 0]      += macc2 * rz;
        op[32 + 3*col + 1]      += macc3 * rz;
        op[32 + 3*col + 2]      += macc4 * rz;
        op[32 + 3*(col+16) + 0] += macc5 * rz;
        op[32 + 3*(col+16) + 1] += macc6 * rz;
        op[32 + 3*(col+16) + 2] += macc7 * rz;
    }
}

extern "C" void kernel_launch(void* const* d_in, const int* in_sizes, int n_in,
                              void* d_out, int out_size, void* d_ws, size_t ws_size,
                              hipStream_t stream)
{
    const float* feats = (const float*)d_in[0];
    const float* attrs = (const float*)d_in[1];
    const float* emb   = (const float*)d_in[2];
    const float* eattr = (const float*)d_in[3];
    // d_in[4] positions: unused (reference computes positions[src]-positions[src] == 0)
    const float* Wq0  = (const float*)d_in[5];
    const float* Wq1  = (const float*)d_in[6];
    const float* Wk1  = (const float*)d_in[7];
    const float* Wk2  = (const float*)d_in[8];
    const float* Wv1  = (const float*)d_in[9];
    const float* Wv2  = (const float*)d_in[10];
    const float* Wlk0 = (const float*)d_in[11];
    const float* Wlk1 = (const float*)d_in[12];
    const float* Wlv0 = (const float*)d_in[13];
    const float* Wlv1 = (const float*)d_in[14];
    const float* Wd0  = (const float*)d_in[15];
    const float* Wd1  = (const float*)d_in[16];
    const float* Ws0  = (const float*)d_in[17];
    const float* Ws1  = (const float*)d_in[18];
    const int*   eidx = (const int*)d_in[19];

    float* out   = (float*)d_out;
    // 16B-aligned workspace layout (float4/half8 streams first):
    float* qdbuf = (float*)d_ws;                              // N*128 f
    float* eattrp = qdbuf + (size_t)N_NODES*128;              // E*4 f (CSR order)
    int*   srcp  = (int*)(eattrp + (size_t)N_EDGES*4);        // E    (CSR order)
    _Float16* feats16 = (_Float16*)(srcp + N_EDGES);          // N*128 h
    _Float16* emb16p  = feats16 + (size_t)N_NODES*128;        // E*16 h (CSR order)
    int*   degb  = (int*)(emb16p + (size_t)N_EDGES*16);       // N
    int*   rowst = degb + N_NODES;                            // N+1
    int*   curs  = rowst + N_NODES + 1;                       // N

    hipMemsetAsync(degb, 0, N_NODES*sizeof(int), stream);
    node_kernel<<<N_NODES/4, 256, 0, stream>>>(feats, attrs, Wq0, Wq1, Wd0, Wd1,
                                               Ws0, Ws1, qdbuf, out, feats16);
    count_kernel<<<N_EDGES/256, 256, 0, stream>>>(eidx, degb);
    scan_kernel<<<1, 256, 0, stream>>>(degb, rowst, curs);
    scatter_kernel<<<N_EDGES/256, 256, 0, stream>>>(eidx, emb, eattr, curs,
                                                    srcp, emb16p, eattrp);
    edge_fused<<<N_NODES/4, 256, 0, stream>>>(feats16, emb16p, eattrp, srcp,
                                              Wk1, Wk2, Wlk0, Wlk1,
                                              Wv1, Wv2, Wlv0, Wlv1,
                                              qdbuf, rowst, out);
}

// Round 2
// 260.250 us; speedup vs baseline: 1.4506x; 1.4506x over previous
//
#include <hip/hip_runtime.h>
#include <math.h>

#define N_NODES 8192
#define N_EDGES 262144
#define INV_SQRT3 0.5773502691896258f

typedef __attribute__((ext_vector_type(8))) _Float16 half8;
typedef __attribute__((ext_vector_type(4))) float floatx4;

#define MF16(a,b,c) __builtin_amdgcn_mfma_f32_16x16x32_f16(a,b,c,0,0,0)

__device__ __forceinline__ float sspf(float x){
    // softplus(x) - ln2 via hw v_exp/v_log
    return (x > 20.0f) ? (x - 0.69314718f)
                       : (__logf(1.0f + __expf(x)) - 0.69314718f);
}

// ---------------------------------------------------------------------------
// Node kernel (factored sc einsum): sc = einsum('nu,nuv->nv', s, T),
// T[n,u,v] = einsum('na,uav->nuv', attrs, Ws). 4 nodes/block.
// Also computes q, qd (= Wd^T q, scales folded), stored PERMUTED:
// qdbuf[n][col*8+slot], slot = {qd0[c], qd0[c+16], qd1[3c..+2], qd1[3(c+16)..+2]}.
// Also emits feats16 (fp16 copy of feats) in the same load loop.
// ---------------------------------------------------------------------------
__global__ __launch_bounds__(256) void node_kernel(
    const float* __restrict__ feats, const float* __restrict__ attrs,
    const float* __restrict__ Wq0, const float* __restrict__ Wq1,
    const float* __restrict__ Wd0, const float* __restrict__ Wd1,
    const float* __restrict__ Ws0, const float* __restrict__ Ws1,
    float* __restrict__ qdbuf, float* __restrict__ out,
    _Float16* __restrict__ feats16)
{
    __shared__ float sa[4][16];
    __shared__ float sT[4][4][32];
    __shared__ float Tl[2][4][1152];   // T, rows stride 36
    __shared__ float qT[4][4][32];
    __shared__ float qsh[4][128];

    const int t  = threadIdx.x;
    const int nb = blockIdx.x * 4;

    const float inv_sqrt32 = 0.17677669529663687f;
    const float sc_scale   = 0.04419417382415922f;
    const float d_scale    = 0.022097086912079608f;

    for (int i = t; i < 512; i += 256){
        int nn = i >> 7, r = i & 127;
        int p = r >> 5, u = r & 31;
        int off = (p==0) ? u : 32 + u*3 + (p-1);
        float val = feats[(size_t)(nb+nn)*128 + off];
        sT[nn][p][u] = val;
        feats16[(size_t)(nb+nn)*128 + off] = (_Float16)val;
    }
    if (t < 64) sa[t>>4][t&15] = attrs[(size_t)(nb + (t>>4))*16 + (t&15)];
    __syncthreads();

    const int v  = t & 31;
    const int g5 = (t >> 5) & 3;
    const int hi = t >> 7;

    {
        const float* __restrict__ Wm = hi ? Ws1 : Ws0;
        float sar[4][16];
        #pragma unroll
        for (int nn = 0; nn < 4; ++nn)
            #pragma unroll
            for (int a = 0; a < 16; ++a) sar[nn][a] = sa[nn][a];
        #pragma unroll
        for (int uu = 0; uu < 8; ++uu){
            int u = g5*8 + uu;
            float a0=0.f, a1=0.f, a2=0.f, a3=0.f;
            #pragma unroll
            for (int a = 0; a < 16; ++a){
                float w = Wm[(u*16 + a)*32 + v];
                a0 += sar[0][a]*w; a1 += sar[1][a]*w;
                a2 += sar[2][a]*w; a3 += sar[3][a]*w;
            }
            Tl[hi][0][v*36+u] = a0; Tl[hi][1][v*36+u] = a1;
            Tl[hi][2][v*36+u] = a2; Tl[hi][3][v*36+u] = a3;
        }
    }
    __syncthreads();

    const int p  = g5;
    const int n0 = hi*2, n1 = n0 + 1;
    const int mm = (p==0) ? 0 : 1;
    const float* __restrict__ Wqp = (p==0) ? Wq0 : Wq1;
    const float* __restrict__ Wdp = (p==0) ? Wd0 : Wd1;
    const int oidx = (p==0) ? v : 32 + v*3 + (p-1);

    float c0=0.f, c1=0.f;
    #pragma unroll
    for (int uc = 0; uc < 8; ++uc){
        float4 t0 = *(const float4*)&Tl[mm][n0][v*36 + uc*4];
        float4 t1 = *(const float4*)&Tl[mm][n1][v*36 + uc*4];
        float4 s0 = *(const float4*)&sT[n0][p][uc*4];
        float4 s1 = *(const float4*)&sT[n1][p][uc*4];
        c0 += t0.x*s0.x + t0.y*s0.y + t0.z*s0.z + t0.w*s0.w;
        c1 += t1.x*s1.x + t1.y*s1.y + t1.z*s1.z + t1.w*s1.w;
    }
    out[(size_t)(nb+n0)*128 + oidx] = c0 * sc_scale;
    out[(size_t)(nb+n1)*128 + oidx] = c1 * sc_scale;

    float q0=0.f, q1=0.f;
    #pragma unroll
    for (int u = 0; u < 32; ++u){
        float w = Wqp[u*32 + v];
        q0 += sT[n0][p][u] * w;
        q1 += sT[n1][p][u] * w;
    }
    qT[n0][p][v] = q0 * inv_sqrt32;
    qT[n1][p][v] = q1 * inv_sqrt32;
    __syncthreads();

    float d0=0.f, d1=0.f;
    #pragma unroll
    for (int u = 0; u < 32; ++u){
        float w = Wdp[u*32 + v];
        d0 += qT[n0][p][u] * w;
        d1 += qT[n1][p][u] * w;
    }
    float dsc = (p==0) ? d_scale : d_scale * INV_SQRT3;
    qsh[n0][oidx] = d0 * dsc;
    qsh[n1][oidx] = d1 * dsc;
    __syncthreads();

    for (int i = t; i < 512; i += 256){
        int nn = i >> 7, tt = i & 127;
        int col = tt >> 3, slot = tt & 7;
        int src;
        if      (slot == 0) src = col;
        else if (slot == 1) src = col + 16;
        else if (slot <  5) src = 32 + 3*col + (slot-2);
        else                src = 32 + 3*(col+16) + (slot-5);
        qdbuf[(size_t)(nb+nn)*128 + tt] = qsh[nn][src];
    }
}

// ---------------------------------------------------------------------------
// CSR build: histogram by dst -> exclusive scan -> scatter+REORDER.
// ---------------------------------------------------------------------------
__global__ __launch_bounds__(256) void count_kernel(
    const int* __restrict__ eidx, int* __restrict__ degb)
{
    int e = blockIdx.x*256 + threadIdx.x;
    atomicAdd(&degb[eidx[N_EDGES + e]], 1);
}

__global__ __launch_bounds__(256) void scan_kernel(
    const int* __restrict__ degb, int* __restrict__ rowstart,
    int* __restrict__ cursor)
{
    __shared__ int part[256];
    int t = threadIdx.x;
    int loc[32];
    int s = 0;
    #pragma unroll
    for (int i = 0; i < 32; ++i){ loc[i] = s; s += degb[t*32 + i]; }
    part[t] = s;
    __syncthreads();
    for (int d = 1; d < 256; d <<= 1){
        int v = (t >= d) ? part[t-d] : 0;
        __syncthreads();
        part[t] += v;
        __syncthreads();
    }
    int excl = part[t] - s;
    #pragma unroll
    for (int i = 0; i < 32; ++i){
        int v = excl + loc[i];
        rowstart[t*32 + i] = v;
        cursor[t*32 + i]   = v;
    }
    if (t == 255) rowstart[N_NODES] = excl + s;
}

__global__ __launch_bounds__(256) void scatter_kernel(
    const int* __restrict__ eidx, const float* __restrict__ emb,
    const float* __restrict__ eattr, int* __restrict__ cursor,
    int* __restrict__ srcp, _Float16* __restrict__ emb16p,
    float* __restrict__ eattrp)
{
    int e = blockIdx.x*256 + threadIdx.x;
    int p = atomicAdd(&cursor[eidx[N_EDGES + e]], 1);
    srcp[p] = eidx[e];
    *(float4*)(eattrp + (size_t)p*4) = *(const float4*)(eattr + (size_t)e*4);
    const float4* ep = (const float4*)(emb + (size_t)e*16);
    float4 v0 = ep[0], v1 = ep[1], v2 = ep[2], v3 = ep[3];
    half8 h0, h1;
    h0[0]=(_Float16)v0.x; h0[1]=(_Float16)v0.y; h0[2]=(_Float16)v0.z; h0[3]=(_Float16)v0.w;
    h0[4]=(_Float16)v1.x; h0[5]=(_Float16)v1.y; h0[6]=(_Float16)v1.z; h0[7]=(_Float16)v1.w;
    h1[0]=(_Float16)v2.x; h1[1]=(_Float16)v2.y; h1[2]=(_Float16)v2.z; h1[3]=(_Float16)v2.w;
    h1[4]=(_Float16)v3.x; h1[5]=(_Float16)v3.y; h1[6]=(_Float16)v3.z; h1[7]=(_Float16)v3.w;
    *(half8*)(emb16p + (size_t)p*16)     = h0;
    *(half8*)(emb16p + (size_t)p*16 + 8) = h1;
}

// ---------------------------------------------------------------------------
// FUSED edge pass — REGISTER-PRESSURE-MINIMIZED rewrite (R1 post-mortem:
// R0 fusion spilled ~60 VGPRs/lane -> 254 MB scratch writes + 331 MB fetch).
// Pressure cuts vs R0:
//  * x-state kept PACKED (hx/hz0/hz1/hz2 half8 = 16 regs, was 32 floats);
//    converted per-use with LITERAL lane indices (no dynamic vec subscript).
//  * every GEMM1/GEMM2 MFMA result staged to LDS immediately (1 floatx4
//    live, was 8).
//  * lin-k results fold into one ddv floatx4 as produced (was 8 floatx4);
//    lin-v results fold straight into macc scalars.
// Math identical to R0: msg = sqrt(ev)*v summed, * rsqrt(z) at end.
// LDS 74752 B -> 2 blocks/CU; same-wave DS in-order covers stag overlays.
// mfma_f32_16x16x32_f16 layouts (measured, learn_hip m89/m120):
// A[m=lane&15][k=quad*8+j]; B[k=quad*8+j][n=lane&15]; C col=lane&15,
// row=quad*4+reg.
// ---------------------------------------------------------------------------

#define G1STAGE(FRAG, OFF) { \
    floatx4 hh = MF16(ea, FRAG, zzero); \
    stag[g][quad*4+0][(OFF)+col] = (_Float16)sspf(hh[0]); \
    stag[g][quad*4+1][(OFF)+col] = (_Float16)sspf(hh[1]); \
    stag[g][quad*4+2][(OFF)+col] = (_Float16)sspf(hh[2]); \
    stag[g][quad*4+3][(OFF)+col] = (_Float16)sspf(hh[3]); }

#define G2STAGE(A0, A1, B0, B1, OFF) { \
    floatx4 wcx = MF16(A0, B0, zzero); wcx = MF16(A1, B1, wcx); \
    stag[g][quad*4+0][(OFF)+col] = (_Float16)wcx[0]; \
    stag[g][quad*4+1][(OFF)+col] = (_Float16)wcx[1]; \
    stag[g][quad*4+2][(OFF)+col] = (_Float16)wcx[2]; \
    stag[g][quad*4+3][(OFF)+col] = (_Float16)wcx[3]; }

#define UVU_J(j, XA, XB, XC, W0, W1, W2, W3) { \
    float ww0=(float)W0[j], ww1=(float)W1[j]; \
    float ww2=(float)W2[j], ww3=(float)W3[j]; \
    float x0 = (float)hx[j]; \
    float xa = (float)XA, xb = (float)XB, xc = (float)XC; \
    fk0s0[j] = (_Float16)(ww0 * x0 * y0); \
    fk0s1[j] = (_Float16)(ww3 * (xa*y1a + xb*y1b + xc*y1c) * INV_SQRT3); \
    fc0s0[j] = (_Float16)(ww1 * x0 * y1a); \
    fc1s0[j] = (_Float16)(ww1 * x0 * y1b); \
    fc2s0[j] = (_Float16)(ww1 * x0 * y1c); \
    fc0s1[j] = (_Float16)(ww2 * xa * y0); \
    fc1s1[j] = (_Float16)(ww2 * xb * y0); \
    fc2s1[j] = (_Float16)(ww2 * xc * y0); }

#define BUILD_FRAGS(W0, W1, W2, W3) \
    UVU_J(0, hz0[0], hz0[1], hz0[2], W0,W1,W2,W3) \
    UVU_J(1, hz0[3], hz0[4], hz0[5], W0,W1,W2,W3) \
    UVU_J(2, hz0[6], hz0[7], hz1[0], W0,W1,W2,W3) \
    UVU_J(3, hz1[1], hz1[2], hz1[3], W0,W1,W2,W3) \
    UVU_J(4, hz1[4], hz1[5], hz1[6], W0,W1,W2,W3) \
    UVU_J(5, hz1[7], hz2[0], hz2[1], W0,W1,W2,W3) \
    UVU_J(6, hz2[2], hz2[3], hz2[4], W0,W1,W2,W3) \
    UVU_J(7, hz2[5], hz2[6], hz2[7], W0,W1,W2,W3)

__global__ __launch_bounds__(256, 2) void edge_fused(
    const _Float16* __restrict__ feats16, const _Float16* __restrict__ emb16p,
    const float* __restrict__ eattrp, const int* __restrict__ srcp,
    const float* __restrict__ Wk1,  const float* __restrict__ Wk2,
    const float* __restrict__ Wlk0, const float* __restrict__ Wlk1,
    const float* __restrict__ Wv1,  const float* __restrict__ Wv2,
    const float* __restrict__ Wlv0, const float* __restrict__ Wlv1,
    const float* __restrict__ qdbuf,
    const int* __restrict__ rowstart,
    float* __restrict__ out)
{
    __shared__ half8 fW1[2][4][64];
    __shared__ half8 fW2[2][16][64];
    __shared__ half8 fL0[2][4][64];
    __shared__ half8 fL1[2][4][64];
    __shared__ _Float16 stag[4][16][136];

    const int t    = threadIdx.x;
    const int lane = t & 63;
    const int col  = lane & 15;
    const int quad = lane >> 4;
    const int g    = t >> 6;

    // ---- preload BOTH weight sets (scales folded) ----
    #pragma unroll
    for (int kv = 0; kv < 2; ++kv){
        const float* __restrict__ W1 = kv ? Wv1  : Wk1;
        const float* __restrict__ W2 = kv ? Wv2  : Wk2;
        const float* __restrict__ L0 = kv ? Wlv0 : Wlk0;
        const float* __restrict__ L1 = kv ? Wlv1 : Wlk1;
        {
            half8 f;
            #pragma unroll
            for (int j = 0; j < 8; ++j){
                int k = quad*8 + j;
                f[j] = (k < 16) ? (_Float16)(W1[k*64 + g*16 + col] * 0.25f) : (_Float16)0.f;
            }
            fW1[kv][g][lane] = f;
        }
        #pragma unroll
        for (int ff = 0; ff < 4; ++ff){
            int fr = g*4 + ff, tile = fr >> 1, s = fr & 1;
            half8 f;
            #pragma unroll
            for (int j = 0; j < 8; ++j)
                f[j] = (_Float16)(W2[(s*32 + quad*8 + j)*128 + tile*16 + col] * 0.125f);
            fW2[kv][fr][lane] = f;
        }
        {
            int tile = g >> 1, s = g & 1;
            half8 f0, f1;
            #pragma unroll
            for (int j = 0; j < 8; ++j){
                int k = (s*32 + quad*8 + j)*32 + tile*16 + col;
                f0[j] = (_Float16)(L0[k] * 0.125f);
                f1[j] = (_Float16)(L1[k] * 0.125f);
            }
            fL0[kv][g][lane] = f0; fL1[kv][g][lane] = f1;
        }
    }
    __syncthreads();     // the only block-wide barrier

    const floatx4 zzero = {0.f, 0.f, 0.f, 0.f};

    const int n  = blockIdx.x*4 + g;
    const int r0 = rowstart[n];
    const int dcount = rowstart[n+1] - r0;

    const float* qdp = qdbuf + (size_t)n*128 + col*8;
    float4 qa = *(const float4*)qdp;
    float4 qb = *(const float4*)(qdp + 4);

    float macc0=0.f, macc1=0.f, macc2=0.f, macc3=0.f;
    float macc4=0.f, macc5=0.f, macc6=0.f, macc7=0.f;
    float zacc = 0.f;

    for (int tb = 0; tb < dcount; tb += 16){
        int slot = tb + col;
        int pc = r0 + ((slot < dcount) ? slot : (dcount-1));

        // ---- A-fragment: emb16p rows SEQUENTIAL (K=16 padded to 32) ----
        half8 ea;
        if (quad < 2){
            ea = *(const half8*)(emb16p + (size_t)pc*16 + quad*8);
        } else {
            #pragma unroll
            for (int j = 0; j < 8; ++j) ea[j] = (_Float16)0.f;
        }

        const int srcm = srcp[pc];
        const _Float16* fsrc = feats16 + (size_t)srcm*128;
        float4 yv = *(const float4*)(eattrp + (size_t)pc*4);
        const float y0 = yv.x, y1a = yv.y, y1b = yv.z, y1c = yv.w;

        // x-state stays PACKED (16 regs total)
        half8 hx  = *(const half8*)(fsrc + quad*8);
        half8 hz0 = *(const half8*)(fsrc + 32 + quad*24);
        half8 hz1 = *(const half8*)(fsrc + 32 + quad*24 + 8);
        half8 hz2 = *(const half8*)(fsrc + 32 + quad*24 + 16);

        // ---- GEMM1 (k AND v, shared A) -> ssp -> staged immediately ----
        G1STAGE(fW1[0][0][lane],   0)
        G1STAGE(fW1[0][1][lane],  16)
        G1STAGE(fW1[0][2][lane],  32)
        G1STAGE(fW1[0][3][lane],  48)
        G1STAGE(fW1[1][0][lane],  64)
        G1STAGE(fW1[1][1][lane],  80)
        G1STAGE(fW1[1][2][lane],  96)
        G1STAGE(fW1[1][3][lane], 112)

        half8 a0k = *(const half8*)&stag[g][col][     quad*8];
        half8 a1k = *(const half8*)&stag[g][col][32 + quad*8];
        half8 a0v = *(const half8*)&stag[g][col][64 + quad*8];
        half8 a1v = *(const half8*)&stag[g][col][96 + quad*8];

        // ---- GEMM2 k: staged immediately (overlay; same-wave DS in-order) -
        G2STAGE(a0k, a1k, fW2[0][ 0][lane], fW2[0][ 1][lane],   0)
        G2STAGE(a0k, a1k, fW2[0][ 2][lane], fW2[0][ 3][lane],  16)
        G2STAGE(a0k, a1k, fW2[0][ 4][lane], fW2[0][ 5][lane],  32)
        G2STAGE(a0k, a1k, fW2[0][ 6][lane], fW2[0][ 7][lane],  48)
        G2STAGE(a0k, a1k, fW2[0][ 8][lane], fW2[0][ 9][lane],  64)
        G2STAGE(a0k, a1k, fW2[0][10][lane], fW2[0][11][lane],  80)
        G2STAGE(a0k, a1k, fW2[0][12][lane], fW2[0][13][lane],  96)
        G2STAGE(a0k, a1k, fW2[0][14][lane], fW2[0][15][lane], 112)

        half8 w0hk = *(const half8*)&stag[g][col][     quad*8];
        half8 w1hk = *(const half8*)&stag[g][col][32 + quad*8];
        half8 w2hk = *(const half8*)&stag[g][col][64 + quad*8];
        half8 w3hk = *(const half8*)&stag[g][col][96 + quad*8];

        // ---- GEMM2 v (k-reads above issue before these overlay writes) ----
        G2STAGE(a0v, a1v, fW2[1][ 0][lane], fW2[1][ 1][lane],   0)
        G2STAGE(a0v, a1v, fW2[1][ 2][lane], fW2[1][ 3][lane],  16)
        G2STAGE(a0v, a1v, fW2[1][ 4][lane], fW2[1][ 5][lane],  32)
        G2STAGE(a0v, a1v, fW2[1][ 6][lane], fW2[1][ 7][lane],  48)
        G2STAGE(a0v, a1v, fW2[1][ 8][lane], fW2[1][ 9][lane],  64)
        G2STAGE(a0v, a1v, fW2[1][10][lane], fW2[1][11][lane],  80)
        G2STAGE(a0v, a1v, fW2[1][12][lane], fW2[1][13][lane],  96)
        G2STAGE(a0v, a1v, fW2[1][14][lane], fW2[1][15][lane], 112)

        // ---- uvu k fragments (literal-indexed converts from packed x) ----
        half8 fk0s0, fk0s1, fc0s0, fc0s1, fc1s0, fc1s1, fc2s0, fc2s1;
        BUILD_FRAGS(w0hk, w1hk, w2hk, w3hk)

        // ---- lin k folded into ddv as produced ----
        floatx4 ddv = zzero;
        {
            floatx4 tk;
            tk = MF16(fk0s0, fL0[0][0][lane], zzero); tk = MF16(fk0s1, fL0[0][1][lane], tk);
            ddv += tk * qa.x;
            tk = MF16(fk0s0, fL0[0][2][lane], zzero); tk = MF16(fk0s1, fL0[0][3][lane], tk);
            ddv += tk * qa.y;
            tk = MF16(fc0s0, fL1[0][0][lane], zzero); tk = MF16(fc0s1, fL1[0][1][lane], tk);
            ddv += tk * qa.z;
            tk = MF16(fc1s0, fL1[0][0][lane], zzero); tk = MF16(fc1s1, fL1[0][1][lane], tk);
            ddv += tk * qa.w;
            tk = MF16(fc2s0, fL1[0][0][lane], zzero); tk = MF16(fc2s1, fL1[0][1][lane], tk);
            ddv += tk * qb.x;
            tk = MF16(fc0s0, fL1[0][2][lane], zzero); tk = MF16(fc0s1, fL1[0][3][lane], tk);
            ddv += tk * qb.y;
            tk = MF16(fc1s0, fL1[0][2][lane], zzero); tk = MF16(fc1s1, fL1[0][3][lane], tk);
            ddv += tk * qb.z;
            tk = MF16(fc2s0, fL1[0][2][lane], zzero); tk = MF16(fc2s1, fL1[0][3][lane], tk);
            ddv += tk * qb.w;
        }

        float cf0, cf1, cf2, cf3;
        #pragma unroll
        for (int r = 0; r < 4; ++r){
            float dd = ddv[r];
            dd += __shfl_xor(dd, 1);
            dd += __shfl_xor(dd, 2);
            dd += __shfl_xor(dd, 4);
            dd += __shfl_xor(dd, 8);
            // cutoff const: diff = pos[src]-pos[src] == 0 (reference bug)
            bool valid = (tb + quad*4 + r) < dcount;
            float ev = valid ? (0.9048374180359595f * __expf(dd)) : 0.f;
            zacc += ev;
            float cf = sqrtf(ev);
            if (r==0) cf0 = cf; else if (r==1) cf1 = cf;
            else if (r==2) cf2 = cf; else cf3 = cf;
        }

        // ---- read back w_v, rebuild fragments (reuse same registers) ----
        {
            half8 w0hv = *(const half8*)&stag[g][col][     quad*8];
            half8 w1hv = *(const half8*)&stag[g][col][32 + quad*8];
            half8 w2hv = *(const half8*)&stag[g][col][64 + quad*8];
            half8 w3hv = *(const half8*)&stag[g][col][96 + quad*8];
            BUILD_FRAGS(w0hv, w1hv, w2hv, w3hv)
        }

        // ---- lin v folded straight into macc scalars ----
        {
            floatx4 tv;
            tv = MF16(fk0s0, fL0[1][0][lane], zzero); tv = MF16(fk0s1, fL0[1][1][lane], tv);
            macc0 += cf0*tv[0] + cf1*tv[1] + cf2*tv[2] + cf3*tv[3];
            tv = MF16(fk0s0, fL0[1][2][lane], zzero); tv = MF16(fk0s1, fL0[1][3][lane], tv);
            macc1 += cf0*tv[0] + cf1*tv[1] + cf2*tv[2] + cf3*tv[3];
            tv = MF16(fc0s0, fL1[1][0][lane], zzero); tv = MF16(fc0s1, fL1[1][1][lane], tv);
            macc2 += cf0*tv[0] + cf1*tv[1] + cf2*tv[2] + cf3*tv[3];
            tv = MF16(fc1s0, fL1[1][0][lane], zzero); tv = MF16(fc1s1, fL1[1][1][lane], tv);
            macc3 += cf0*tv[0] + cf1*tv[1] + cf2*tv[2] + cf3*tv[3];
            tv = MF16(fc2s0, fL1[1][0][lane], zzero); tv = MF16(fc2s1, fL1[1][1][lane], tv);
            macc4 += cf0*tv[0] + cf1*tv[1] + cf2*tv[2] + cf3*tv[3];
            tv = MF16(fc0s0, fL1[1][2][lane], zzero); tv = MF16(fc0s1, fL1[1][3][lane], tv);
            macc5 += cf0*tv[0] + cf1*tv[1] + cf2*tv[2] + cf3*tv[3];
            tv = MF16(fc1s0, fL1[1][2][lane], zzero); tv = MF16(fc1s1, fL1[1][3][lane], tv);
            macc6 += cf0*tv[0] + cf1*tv[1] + cf2*tv[2] + cf3*tv[3];
            tv = MF16(fc2s0, fL1[1][2][lane], zzero); tv = MF16(fc2s1, fL1[1][3][lane], tv);
            macc7 += cf0*tv[0] + cf1*tv[1] + cf2*tv[2] + cf3*tv[3];
        }
    }

    // ---- reduce over quads; rsqrt(z) factored scaling; write out ----
    macc0 += __shfl_xor(macc0, 16); macc0 += __shfl_xor(macc0, 32);
    macc1 += __shfl_xor(macc1, 16); macc1 += __shfl_xor(macc1, 32);
    macc2 += __shfl_xor(macc2, 16); macc2 += __shfl_xor(macc2, 32);
    macc3 += __shfl_xor(macc3, 16); macc3 += __shfl_xor(macc3, 32);
    macc4 += __shfl_xor(macc4, 16); macc4 += __shfl_xor(macc4, 32);
    macc5 += __shfl_xor(macc5, 16); macc5 += __shfl_xor(macc5, 32);
    macc6 += __shfl_xor(macc6, 16); macc6 += __shfl_xor(macc6, 32);
    macc7 += __shfl_xor(macc7, 16); macc7 += __shfl_xor(macc7, 32);
    zacc  += __shfl_xor(zacc, 16);  zacc  += __shfl_xor(zacc, 32);
    float rz = (zacc > 0.f) ? rsqrtf(zacc) : 0.f;

    if (lane < 16){
        float* op = out + (size_t)n*128;
        op[col]                 += macc0 * rz;
        op[col + 16]            += macc1 * rz;
        op[32 + 3*col + 0]      += macc2 * rz;
        op[32 + 3*col + 1]      += macc3 * rz;
        op[32 + 3*col + 2]      += macc4 * rz;
        op[32 + 3*(col+16) + 0] += macc5 * rz;
        op[32 + 3*(col+16) + 1] += macc6 * rz;
        op[32 + 3*(col+16) + 2] += macc7 * rz;
    }
}

extern "C" void kernel_launch(void* const* d_in, const int* in_sizes, int n_in,
                              void* d_out, int out_size, void* d_ws, size_t ws_size,
                              hipStream_t stream)
{
    const float* feats = (const float*)d_in[0];
    const float* attrs = (const float*)d_in[1];
    const float* emb   = (const float*)d_in[2];
    const float* eattr = (const float*)d_in[3];
    // d_in[4] positions: unused (reference computes positions[src]-positions[src] == 0)
    const float* Wq0  = (const float*)d_in[5];
    const float* Wq1  = (const float*)d_in[6];
    const float* Wk1  = (const float*)d_in[7];
    const float* Wk2  = (const float*)d_in[8];
    const float* Wv1  = (const float*)d_in[9];
    const float* Wv2  = (const float*)d_in[10];
    const float* Wlk0 = (const float*)d_in[11];
    const float* Wlk1 = (const float*)d_in[12];
    const float* Wlv0 = (const float*)d_in[13];
    const float* Wlv1 = (const float*)d_in[14];
    const float* Wd0  = (const float*)d_in[15];
    const float* Wd1  = (const float*)d_in[16];
    const float* Ws0  = (const float*)d_in[17];
    const float* Ws1  = (const float*)d_in[18];
    const int*   eidx = (const int*)d_in[19];

    float* out   = (float*)d_out;
    // 16B-aligned workspace layout (float4/half8 streams first):
    float* qdbuf = (float*)d_ws;                              // N*128 f
    float* eattrp = qdbuf + (size_t)N_NODES*128;              // E*4 f (CSR order)
    int*   srcp  = (int*)(eattrp + (size_t)N_EDGES*4);        // E    (CSR order)
    _Float16* feats16 = (_Float16*)(srcp + N_EDGES);          // N*128 h
    _Float16* emb16p  = feats16 + (size_t)N_NODES*128;        // E*16 h (CSR order)
    int*   degb  = (int*)(emb16p + (size_t)N_EDGES*16);       // N
    int*   rowst = degb + N_NODES;                            // N+1
    int*   curs  = rowst + N_NODES + 1;                       // N

    hipMemsetAsync(degb, 0, N_NODES*sizeof(int), stream);
    node_kernel<<<N_NODES/4, 256, 0, stream>>>(feats, attrs, Wq0, Wq1, Wd0, Wd1,
                                               Ws0, Ws1, qdbuf, out, feats16);
    count_kernel<<<N_EDGES/256, 256, 0, stream>>>(eidx, degb);
    scan_kernel<<<1, 256, 0, stream>>>(degb, rowst, curs);
    scatter_kernel<<<N_EDGES/256, 256, 0, stream>>>(eidx, emb, eattr, curs,
                                                    srcp, emb16p, eattrp);
    edge_fused<<<N_NODES/4, 256, 0, stream>>>(feats16, emb16p, eattrp, srcp,
                                              Wk1, Wk2, Wlk0, Wlk1,
                                              Wv1, Wv2, Wlv0, Wlv1,
                                              qdbuf, rowst, out);
}